// Round 3
// baseline (74.287 us; speedup 1.0000x reference)
//
#include <hip/hip_runtime.h>

// RandomFlipLR: (B=64, C=3, H=512, W=512) fp32, flip W per batch where mask[b]>0.
// Pure memory-bound streaming: 192 MiB in + 192 MiB out, zero reuse.
// - float4 (16B/lane) loads/stores, coalesced on output
// - flipped source index = idx ^ 127 (128 float4/row, subtract-from-ones == XOR)
// - 16 float4 per thread in contiguous 64KiB/block chunks (deep MLP, fewer blocks)
// - nontemporal hints: streaming data, don't thrash L2/L3

typedef float f4 __attribute__((ext_vector_type(4)));

#define B_ 64
#define C_ 3
#define H_ 512
#define W_ 512
#define WV (W_ / 4)              // 128 float4 per row
#define PER_B (C_ * H_ * WV)     // 196608 float4 per batch image
#define ITERS 16
#define CHUNK (256 * ITERS)      // 4096 float4 per block = 64 KiB

__global__ __launch_bounds__(256) void RandomFlipLR_71734543777923_kernel(
    const f4* __restrict__ in, const int* __restrict__ mask,
    f4* __restrict__ out) {
    const int b = blockIdx.y;
    const long long base = (long long)b * PER_B;
    const int tid   = threadIdx.x;
    const int chunk = blockIdx.x * CHUNK;

    f4 v[ITERS];
    if (mask[b] > 0) {                        // wave-uniform branch
        #pragma unroll
        for (int i = 0; i < ITERS; ++i) {
            const int idx = chunk + i * 256 + tid;
            f4 t = __builtin_nontemporal_load(&in[base + (idx ^ (WV - 1))]);
            v[i] = t.wzyx;
        }
    } else {
        #pragma unroll
        for (int i = 0; i < ITERS; ++i) {
            const int idx = chunk + i * 256 + tid;
            v[i] = __builtin_nontemporal_load(&in[base + idx]);
        }
    }
    #pragma unroll
    for (int i = 0; i < ITERS; ++i) {
        const int idx = chunk + i * 256 + tid;
        __builtin_nontemporal_store(v[i], &out[base + idx]);
    }
}

extern "C" void kernel_launch(void* const* d_in, const int* in_sizes, int n_in,
                              void* d_out, int out_size, void* d_ws, size_t ws_size,
                              hipStream_t stream) {
    const f4* in    = (const f4*)d_in[0];
    const int* mask = (const int*)d_in[1];
    f4* out         = (f4*)d_out;

    dim3 block(256);
    dim3 grid(PER_B / CHUNK, B_);            // 48 x 64 = 3072 blocks
    RandomFlipLR_71734543777923_kernel<<<grid, block, 0, stream>>>(in, mask, out);
}

// Round 4
// 70.651 us; speedup vs baseline: 1.0515x; 1.0515x over previous
//
#include <hip/hip_runtime.h>

// RandomFlipLR: (B=64, C=3, H=512, W=512) fp32, flip W per batch where mask[b]>0.
// Pure memory-bound streaming: 192 MiB in + 192 MiB out, zero reuse.
// - float4 (16B/lane) loads/stores, coalesced
// - flipped source index = idx ^ 127 (128 float4/row, subtract-from-ones == XOR)
// - 8 float4 per thread per chunk (32 KiB/block/chunk) — best measured config
// - persistent grid: 2048 blocks (8/CU, full occupancy) x 3 chunks each,
//   cuts dispatch/drain overhead and tail imbalance vs 6144 one-shot blocks
// - nontemporal hints: streaming data, don't thrash L2/L3

typedef float f4 __attribute__((ext_vector_type(4)));

#define B_ 64
#define C_ 3
#define H_ 512
#define W_ 512
#define WV (W_ / 4)               // 128 float4 per row
#define PER_B (C_ * H_ * WV)      // 196608 float4 per batch image
#define ITERS 8
#define CHUNK (256 * ITERS)       // 2048 float4 per chunk = 32 KiB
#define CPB (PER_B / CHUNK)       // 96 chunks per batch
#define NCHUNK (B_ * CPB)         // 6144 total chunks
#define GRID 2048                 // 8 blocks/CU * 256 CU
#define PASSES (NCHUNK / GRID)    // 3

__global__ __launch_bounds__(256) void RandomFlipLR_71734543777923_kernel(
    const f4* __restrict__ in, const int* __restrict__ mask,
    f4* __restrict__ out) {
    const int tid = threadIdx.x;

    #pragma unroll
    for (int p = 0; p < PASSES; ++p) {
        const int g  = blockIdx.x + p * GRID;    // chunk id [0, 6144)
        const int b  = g / CPB;                  // magic-mul, wave-uniform
        const int cx = g - b * CPB;
        const long long base = (long long)b * PER_B;
        const int chunk = cx * CHUNK;

        f4 v[ITERS];
        if (mask[b] > 0) {                       // wave-uniform branch
            #pragma unroll
            for (int i = 0; i < ITERS; ++i) {
                const int idx = chunk + i * 256 + tid;
                f4 t = __builtin_nontemporal_load(&in[base + (idx ^ (WV - 1))]);
                v[i] = t.wzyx;
            }
        } else {
            #pragma unroll
            for (int i = 0; i < ITERS; ++i) {
                const int idx = chunk + i * 256 + tid;
                v[i] = __builtin_nontemporal_load(&in[base + idx]);
            }
        }
        #pragma unroll
        for (int i = 0; i < ITERS; ++i) {
            const int idx = chunk + i * 256 + tid;
            __builtin_nontemporal_store(v[i], &out[base + idx]);
        }
    }
}

extern "C" void kernel_launch(void* const* d_in, const int* in_sizes, int n_in,
                              void* d_out, int out_size, void* d_ws, size_t ws_size,
                              hipStream_t stream) {
    const f4* in    = (const f4*)d_in[0];
    const int* mask = (const int*)d_in[1];
    f4* out         = (f4*)d_out;

    RandomFlipLR_71734543777923_kernel<<<dim3(GRID), dim3(256), 0, stream>>>(in, mask, out);
}